// Round 3
// baseline (526.035 us; speedup 1.0000x reference)
//
#include <hip/hip_runtime.h>

#define K_TAGS 50
#define T_MAX 256
#define START_TAG 48
#define END_TAG 49
#define LOG2E 1.4426950408889634f
#define LN2 0.6931471805599453f
#define KK 2500   // dwords per 50x50 step matrix

// hardware transcendentals: v_exp_f32 is 2^x, v_log_f32 is log2(x)
#define EXP2F(x) __builtin_amdgcn_exp2f(x)
#define LOG2F(x) __builtin_amdgcn_logf(x)

__device__ __forceinline__ float rdlane(float v, int i) {
    return __int_as_float(__builtin_amdgcn_readlane(__float_as_int(v), i));
}

// Raw barrier WITHOUT the __syncthreads vmcnt(0) drain. sched_barrier(0) on both
// sides pins code motion (rule #18: compiler will hoist reg-only ops past inline
// waits otherwise). Producers drain lgkmcnt(0) (ds_write visibility) before it;
// global loads stay in flight across the barrier (T4 counted-vmcnt pattern).
__device__ __forceinline__ void barrier_nodrain() {
    __builtin_amdgcn_sched_barrier(0);
    __builtin_amdgcn_s_barrier();
    __builtin_amdgcn_sched_barrier(0);
}

// PRODUCER/CONSUMER WAVE SPECIALIZATION, one direction per block.
//   grid = 2*B blocks of 256 threads: block (2b+0) = FORWARD half of batch b,
//   block (2b+1) = BACKWARD half. 256 blocks ~ 1 per CU; each wave on its own SIMD.
// wave 0  = consumer: per step 25x ds_read_b64 + 50 readlane*FMA + exponent rescale.
// waves 1-3 = producers: 17 rows each; 4-deep global-load register pipeline,
//   exp + transposed stage into double-buffered LDS.
// One raw s_barrier per step. vmcnt NEVER drained in the loop (the round-2 bug:
// __syncthreads => s_waitcnt vmcnt(0) killed the load pipeline every step).
// Split: fwd covers t=1..m, bwd folds t=len-1 then t=len-2..m+1, m=(len-2)/2.
// Results u (fwd) and v (bwd) -> workspace; combine kernel does Z = u.v.
__global__ __launch_bounds__(256, 1) void crf_fwd_kernel(
    const float* __restrict__ scores, const int* __restrict__ targets,
    const int* __restrict__ lengths, float* __restrict__ accum,
    float* __restrict__ uv)
{
    const int b    = blockIdx.x >> 1;
    const int dir  = blockIdx.x & 1;      // 0 = forward, 1 = backward
    const int tid  = threadIdx.x;
    const int wave = tid >> 6;
    const int lane = tid & 63;
    const int len  = lengths[b];
    const float* __restrict__ sp = scores + (size_t)b * T_MAX * KK;

    __shared__ float buf[2 * KK];         // double-buffered exp'd step matrix (20 KB)

    const int m = (len - 2) / 2;          // fwd steps t=1..m
    int count = dir ? (len - 2 - m) : m;  // recurrence steps this block runs
    if (count < 0) count = 0;
    const int nmac = (count + 3) >> 2;

    // ---- gold score: fwd block only, one timestep per thread (256 thr) ----
    if (dir == 0) {
        float g = 0.f;
        if (tid < len) g = sp[(size_t)tid * KK + targets[b * T_MAX + tid]];
        #pragma unroll
        for (int off = 32; off; off >>= 1) g += __shfl_down(g, off, 64);
        if (lane == 0) atomicAdd(&accum[1], g);
    }

    if (wave == 0) {
        // =========================== consumer ===========================
        const int j = (lane < K_TAGS) ? lane : (K_TAGS - 1);
        float L, M;
        if (dir == 0) {
            float bcur = sp[START_TAG * K_TAGS + j] * LOG2E;   // t=0, row START
            M = rdlane(bcur, 0);
            L = EXP2F(bcur - M);
        } else {
            M = 0.f;
            if (len >= 2)   // fold t=len-1: v = exp(s[:,END])
                L = EXP2F(sp[(size_t)(len - 1) * KK + j * K_TAGS + END_TAG] * LOG2E);
            else
                L = (j == END_TAG) ? 1.f : 0.f;
        }
        barrier_nodrain();                // prologue: buf parity 0 ready

        for (int mi = 0; mi < nmac; ++mi) {
            const int s0 = mi << 2;
            #pragma unroll
            for (int k = 0; k < 4; ++k) {
                if (s0 + k < count) {
                    const float2* br =
                        (const float2*)(buf + (k & 1) * KK + j * K_TAGS);
                    float R[50];
                    #pragma unroll
                    for (int q = 0; q < 25; ++q)
                        *(float2*)&R[2 * q] = br[q];
                    float l0 = rdlane(L, 0);
                    int   ei = (__float_as_int(l0) >> 23) & 0xFF;
                    float scale = __int_as_float((254 - ei) << 23);
                    float a0 = 0.f, a1 = 0.f, a2 = 0.f, a3 = 0.f, a4 = 0.f;
                    #pragma unroll
                    for (int i = 0; i < 50; i += 5) {
                        a0 = __builtin_fmaf(R[i + 0], rdlane(L, i + 0), a0);
                        a1 = __builtin_fmaf(R[i + 1], rdlane(L, i + 1), a1);
                        a2 = __builtin_fmaf(R[i + 2], rdlane(L, i + 2), a2);
                        a3 = __builtin_fmaf(R[i + 3], rdlane(L, i + 3), a3);
                        a4 = __builtin_fmaf(R[i + 4], rdlane(L, i + 4), a4);
                    }
                    L = (((a0 + a1) + (a2 + a3)) + a4) * scale;
                    M += (float)(ei - 127);
                }
                barrier_nodrain();
            }
        }
        // publish result vector for the combine kernel
        float* w = uv + (size_t)(dir ? (gridDim.x >> 1) + b : b) * 64;
        if (lane < K_TAGS) w[lane] = L;
        if (lane == 0)     w[K_TAGS] = M;
    } else {
        // =========================== producers ==========================
        const int  r0  = 17 * (wave - 1);               // row range [r0, r0+17)
        const bool act = lane < K_TAGS;
        const int  j   = act ? lane : (K_TAGS - 1);
        float S[4][17];                                  // 4-deep load pipeline

        // matrix index for recurrence step s
        auto tof = [&](int s) { return dir ? (len - 2 - s) : (s + 1); };

        // prologue: issue loads for steps 0..2; exp+write step 0 -> parity 0
        #pragma unroll
        for (int q = 0; q < 3; ++q) {
            if (q < count && act) {
                const float* p = sp + (size_t)tof(q) * KK + j;
                #pragma unroll
                for (int r = 0; r < 17; ++r)
                    if (r0 + r < K_TAGS) S[q][r] = p[(r0 + r) * K_TAGS];
            }
        }
        __builtin_amdgcn_sched_barrier(0);
        if (0 < count && act) {
            #pragma unroll
            for (int r = 0; r < 17; ++r)
                if (r0 + r < K_TAGS) {
                    int   row = r0 + r;
                    float e = EXP2F(S[0][r] * LOG2E);
                    buf[dir ? (row * K_TAGS + j) : (j * K_TAGS + row)] = e;
                }
        }
        asm volatile("s_waitcnt lgkmcnt(0)" ::: "memory");
        barrier_nodrain();

        for (int mi = 0; mi < nmac; ++mi) {
            const int s0 = mi << 2;
            #pragma unroll
            for (int k = 0; k < 4; ++k) {
                // issue loads for step s0+k+3 into set (k+3)&3  (3-step latency gap)
                if (s0 + k + 3 < count && act) {
                    const float* p = sp + (size_t)tof(s0 + k + 3) * KK + j;
                    #pragma unroll
                    for (int r = 0; r < 17; ++r)
                        if (r0 + r < K_TAGS) S[(k + 3) & 3][r] = p[(r0 + r) * K_TAGS];
                }
                __builtin_amdgcn_sched_barrier(0);
                // exp + stage step s0+k+1 into parity (k+1)&1
                if (s0 + k + 1 < count && act) {
                    float* bw = buf + ((k + 1) & 1) * KK;
                    #pragma unroll
                    for (int r = 0; r < 17; ++r)
                        if (r0 + r < K_TAGS) {
                            int   row = r0 + r;
                            float e = EXP2F(S[(k + 1) & 3][r] * LOG2E);
                            bw[dir ? (row * K_TAGS + j) : (j * K_TAGS + row)] = e;
                        }
                }
                asm volatile("s_waitcnt lgkmcnt(0)" ::: "memory");
                barrier_nodrain();
            }
        }
    }
}

// per-batch combine: Z_b = Mu + Mv + log2(sum_j u[j]*v[j])
__global__ void combine_kernel(const float* __restrict__ uv,
                               float* __restrict__ accum, int B)
{
    const int b = blockIdx.x, lane = threadIdx.x;
    const float* U = uv + (size_t)b * 64;
    const float* V = uv + (size_t)(B + b) * 64;
    float prod = (lane < K_TAGS) ? U[lane] * V[lane] : 0.f;
    #pragma unroll
    for (int off = 32; off; off >>= 1) prod += __shfl_down(prod, off, 64);
    if (lane == 0) {
        float z = (U[K_TAGS] + V[K_TAGS] + LOG2F(prod)) * LN2;
        atomicAdd(&accum[0], z);
    }
}

__global__ void finalize_kernel(const float* __restrict__ accum,
                                float* __restrict__ out, float invB)
{
    out[0] = (accum[0] - accum[1]) * invB;
}

extern "C" void kernel_launch(void* const* d_in, const int* in_sizes, int n_in,
                              void* d_out, int out_size, void* d_ws, size_t ws_size,
                              hipStream_t stream)
{
    const float* scores  = (const float*)d_in[0];
    const int*   targets = (const int*)d_in[1];
    const int*   lengths = (const int*)d_in[2];
    const int B = in_sizes[2];

    float* accum = (float*)d_ws;
    float* uv    = (float*)d_ws + 16;     // u[B][64] then v[B][64]
    hipMemsetAsync(accum, 0, 2 * sizeof(float), stream);
    crf_fwd_kernel<<<2 * B, 256, 0, stream>>>(scores, targets, lengths, accum, uv);
    combine_kernel<<<B, 64, 0, stream>>>(uv, accum, B);
    finalize_kernel<<<1, 1, 0, stream>>>(accum, (float*)d_out, 1.0f / (float)B);
}

// Round 4
// 421.101 us; speedup vs baseline: 1.2492x; 1.2492x over previous
//
#include <hip/hip_runtime.h>

#define K_TAGS 50
#define T_MAX 256
#define START_TAG 48
#define END_TAG 49
#define LOG2E 1.4426950408889634f
#define LN2 0.6931471805599453f
#define KK 2500   // dwords per 50x50 step matrix

// hardware transcendentals: v_exp_f32 is 2^x, v_log_f32 is log2(x)
#define EXP2F(x) __builtin_amdgcn_exp2f(x)
#define LOG2F(x) __builtin_amdgcn_logf(x)

__device__ __forceinline__ float rdlane(float v, int i) {
    return __int_as_float(__builtin_amdgcn_readlane(__float_as_int(v), i));
}

// Raw barrier with LDS-only drain. 0xC07F = vmcnt(63) expcnt(7) lgkmcnt(0):
// waits ds_write visibility WITHOUT draining the global-load pipeline.
// Builtin (not inline asm!) so SIInsertWaitcnts keeps counted vmcnt for loads
// (rounds 2/3 failure: asm volatile w/ "memory" clobber => conservative full
// drain each step => ~3670 cyc/step). sched_barrier(0) pins code motion.
__device__ __forceinline__ void barrier_lds() {
    __builtin_amdgcn_sched_barrier(0);
    __builtin_amdgcn_s_waitcnt(0xC07F);
    __builtin_amdgcn_s_barrier();
    __builtin_amdgcn_sched_barrier(0);
}

// SYMMETRIC SPLIT-i, one direction per block, NO producer/consumer asymmetry.
//   grid = 2*B blocks x 256 thr: block (2b+0) = FORWARD half of batch b,
//   block (2b+1) = BACKWARD half, meeting at m=(len-2)/2. 256 blocks ~ 1/CU.
// All 4 waves identical: wave w owns matrix rows [13w, 13w+13) (wave 3: 11 live
// rows, 2 zero-masked). Lane j owns column j (lanes 50-63 duplicate col 49).
// Per step, per wave:  13 coalesced loads (4-deep reg pipeline, imm offsets)
//   + 13 exps + 13 readlane*FMA partial + 1 ds_write -> barrier ->
//   4 ds_read partials + sum + exponent rescale (replicated in every wave so
//   each wave keeps the full L vector in-register for readlane broadcasts).
// Scaled-linear numerics identical to prior rounds: true log2-val = M + log2(L).
__global__ __launch_bounds__(256, 1) void crf_fwd_kernel(
    const float* __restrict__ scores, const int* __restrict__ targets,
    const int* __restrict__ lengths, float* __restrict__ accum,
    float* __restrict__ uv)
{
    const int b    = blockIdx.x >> 1;
    const int dir  = blockIdx.x & 1;      // 0 = forward, 1 = backward
    const int tid  = threadIdx.x;
    const int wave = tid >> 6;
    const int lane = tid & 63;
    const int len  = lengths[b];
    const float* __restrict__ sp = scores + (size_t)b * T_MAX * KK;
    const int jc = (lane < K_TAGS) ? lane : (K_TAGS - 1);

    __shared__ float pbuf[2][4 * 64];     // double-buffered per-wave partials (2 KB)

    const int m = (len - 2) / 2;          // fwd applies G_t, t=1..m
    int count = dir ? (len - 2 - m) : m;  // steps this block runs
    if (count < 0) count = 0;

    // ---- gold score: fwd block only, one timestep per thread ----
    if (dir == 0) {
        float g = 0.f;
        if (tid < len) g = sp[(size_t)tid * KK + targets[b * T_MAX + tid]];
        #pragma unroll
        for (int off = 32; off; off >>= 1) g += __shfl_down(g, off, 64);
        if (lane == 0) atomicAdd(&accum[1], g);
    }

    // ---- init L/M, replicated in every wave ----
    float L, M;
    if (dir == 0) {
        float bc = sp[START_TAG * K_TAGS + jc] * LOG2E;   // alpha0 row
        M = rdlane(bc, 0);
        L = EXP2F(bc - M);
    } else {
        M = 0.f;
        if (len >= 2)   // fold t=len-1: v = exp(s[:,END])
            L = EXP2F(sp[(size_t)(len - 1) * KK + jc * K_TAGS + END_TAG] * LOG2E);
        else
            L = (jc == END_TAG) ? 1.f : 0.f;
    }

    const int rb = 13 * wave;             // first owned row

    if (count > 0) {
        // matrix time for (clamped) step index
        auto tof = [&](int s) {
            int ss = (s <= count) ? s : count;
            return dir ? (len - 1 - ss) : ss;
        };

        float S[4][13], P[2][13];

        // rows rb..rb+12 unclamped: max addr = 254*KK + 51*50 + 49 < T_MAX*KK, in
        // bounds even for wave 3's 2 dead rows (their P is zero-masked below).
        auto loadset = [&](int set, int s) {
            const float* base = sp + (size_t)tof(s) * KK + rb * K_TAGS + jc;
            #pragma unroll
            for (int r = 0; r < 13; ++r) S[set][r] = base[r * K_TAGS];
        };
        auto expset = [&](int pd, int ss) {
            #pragma unroll
            for (int r = 0; r < 13; ++r) {
                float e = EXP2F(S[ss][r] * LOG2E);
                if (r >= 11 && rb + r >= K_TAGS) e = 0.f;   // wave-3 dead rows
                P[pd][r] = e;
            }
        };

        // prologue: steps 1..4 -> S[1],S[2],S[3],S[0]; exp step 1 -> P[1]
        #pragma unroll
        for (int q = 1; q <= 4; ++q) loadset(q & 3, q);
        expset(1, 1);

        for (int s0 = 1; s0 <= count; s0 += 4) {
            #pragma unroll
            for (int k = 0; k < 4; ++k) {
                const int  st  = s0 + k;             // current step (applies G_tof(st))
                const int  SS  = (k + 1) & 3;        // st&3  : set freed by last exp
                const int  SSn = (k + 2) & 3;        // (st+1)&3: set to exp now
                const int  PP  = (k + 1) & 1;        // st&1  : P consumed, parity written
                const int  PPn = k & 1;              // (st+1)&1: P produced
                const bool live = (st <= count);     // block-uniform

                // A) prefetch loads for step st+4 (kept in flight across barriers)
                if (live) loadset(SS, st + 4);

                // B) partial mat-vec for step st: a = sum_{r} P[r] * L[rb+r]
                if (live) {
                    float a0 = 0.f, a1 = 0.f, a2 = 0.f;
                    #pragma unroll
                    for (int r = 0; r < 13; r += 3) {
                        a0 = __builtin_fmaf(P[PP][r], rdlane(L, rb + r), a0);
                        if (r + 1 < 13)
                            a1 = __builtin_fmaf(P[PP][r + 1], rdlane(L, rb + r + 1), a1);
                        if (r + 2 < 13)
                            a2 = __builtin_fmaf(P[PP][r + 2], rdlane(L, rb + r + 2), a2);
                    }
                    if (lane < K_TAGS)
                        pbuf[PP][(wave << 6) + lane] = (a0 + a1) + a2;
                }

                // C) exp step st+1 off the critical path (inputs loaded >=3 steps ago)
                expset(PPn, SSn);

                // D) all partials visible (lgkm only; vmcnt stays counted)
                barrier_lds();

                // E) combine partials + rescale (every wave, so L stays replicated)
                if (live) {
                    float p0 = pbuf[PP][jc];
                    float p1 = pbuf[PP][64 + jc];
                    float p2 = pbuf[PP][128 + jc];
                    float p3 = pbuf[PP][192 + jc];
                    float sum = (p0 + p1) + (p2 + p3);
                    int   ei = (__float_as_int(rdlane(sum, 0)) >> 23) & 0xFF;
                    float scale = __int_as_float((254 - ei) << 23);   // 2^-(ei-127)
                    L = sum * scale;
                    M += (float)(ei - 127);
                }
            }
        }
    }

    // ---- publish result vector for the combine kernel ----
    if (wave == 0) {
        float* w = uv + (size_t)(dir ? (gridDim.x >> 1) + b : b) * 64;
        if (lane < K_TAGS) w[lane] = L;
        if (lane == 0)     w[K_TAGS] = M;
    }
}

// per-batch combine: Z_b = Mu + Mv + log2(sum_j u[j]*v[j])
__global__ void combine_kernel(const float* __restrict__ uv,
                               float* __restrict__ accum, int B)
{
    const int b = blockIdx.x, lane = threadIdx.x;
    const float* U = uv + (size_t)b * 64;
    const float* V = uv + (size_t)(B + b) * 64;
    float prod = (lane < K_TAGS) ? U[lane] * V[lane] : 0.f;
    #pragma unroll
    for (int off = 32; off; off >>= 1) prod += __shfl_down(prod, off, 64);
    if (lane == 0) {
        float z = (U[K_TAGS] + V[K_TAGS] + LOG2F(prod)) * LN2;
        atomicAdd(&accum[0], z);
    }
}

__global__ void finalize_kernel(const float* __restrict__ accum,
                                float* __restrict__ out, float invB)
{
    out[0] = (accum[0] - accum[1]) * invB;
}

extern "C" void kernel_launch(void* const* d_in, const int* in_sizes, int n_in,
                              void* d_out, int out_size, void* d_ws, size_t ws_size,
                              hipStream_t stream)
{
    const float* scores  = (const float*)d_in[0];
    const int*   targets = (const int*)d_in[1];
    const int*   lengths = (const int*)d_in[2];
    const int B = in_sizes[2];

    float* accum = (float*)d_ws;
    float* uv    = (float*)d_ws + 16;     // u[B][64] then v[B][64]
    hipMemsetAsync(accum, 0, 2 * sizeof(float), stream);
    crf_fwd_kernel<<<2 * B, 256, 0, stream>>>(scores, targets, lengths, accum, uv);
    combine_kernel<<<B, 64, 0, stream>>>(uv, accum, B);
    finalize_kernel<<<1, 1, 0, stream>>>(accum, (float*)d_out, 1.0f / (float)B);
}